// Round 1
// baseline (839.058 us; speedup 1.0000x reference)
//
#include <hip/hip_runtime.h>
#include <math.h>

#define N_NODES 100000
#define E_EDGES 1600000
#define HDIM 128
#define NEG_SLOPE 0.01f
#define EPS_DEN 1e-16f

// ---- orderable-uint encoding for float atomicMax ----
__device__ __forceinline__ unsigned enc_f32(float f) {
    unsigned u = __float_as_uint(f);
    return (u & 0x80000000u) ? ~u : (u | 0x80000000u);
}
__device__ __forceinline__ float dec_f32(unsigned u) {
    return (u & 0x80000000u) ? __uint_as_float(u & 0x7FFFFFFFu)
                             : __uint_as_float(~u);
}

// K1: per-node scores s_i = x.w_i, s_j = x.w_j  (one wave per node)
__global__ __launch_bounds__(256) void k_scores(
    const float* __restrict__ x, const float* __restrict__ w_i,
    const float* __restrict__ w_j, float* __restrict__ s_i,
    float* __restrict__ s_j) {
    int wave = (blockIdx.x * blockDim.x + threadIdx.x) >> 6;
    int lane = threadIdx.x & 63;
    if (wave >= N_NODES) return;
    const float* row = x + (size_t)wave * HDIM;
    float a0 = row[lane];
    float a1 = row[lane + 64];
    float vi = a0 * w_i[lane] + a1 * w_i[lane + 64];
    float vj = a0 * w_j[lane] + a1 * w_j[lane + 64];
#pragma unroll
    for (int off = 32; off; off >>= 1) {
        vi += __shfl_down(vi, off);
        vj += __shfl_down(vj, off);
    }
    if (lane == 0) {
        s_i[wave] = vi;
        s_j[wave] = vj;
    }
}

// K2: per-edge raw score e = leaky_relu(s_i[i] + s_j[j]); segment max over j
__global__ __launch_bounds__(256) void k_edge_max(
    const int* __restrict__ ej, const int* __restrict__ ei,
    const float* __restrict__ s_i, const float* __restrict__ s_j,
    float* __restrict__ e_buf, unsigned* __restrict__ segmax) {
    int t = blockIdx.x * blockDim.x + threadIdx.x;
    if (t >= E_EDGES) return;
    int j = ej[t];
    int i = ei[t];
    float e = s_i[i] + s_j[j];
    e = e > 0.f ? e : NEG_SLOPE * e;
    e_buf[t] = e;
    atomicMax(&segmax[j], enc_f32(e));
}

// K3: ex = exp(e - max[j]); denom[j] += ex   (ex written in place over e)
__global__ __launch_bounds__(256) void k_edge_exp(
    const int* __restrict__ ej, float* __restrict__ e_buf,
    const unsigned* __restrict__ segmax, float* __restrict__ denom) {
    int t = blockIdx.x * blockDim.x + threadIdx.x;
    if (t >= E_EDGES) return;
    int j = ej[t];
    float m = dec_f32(segmax[j]);
    float ex = expf(e_buf[t] - m);
    e_buf[t] = ex;
    atomicAdd(&denom[j], ex);
}

// K4: SPMM — one wave per edge: out[i] += alpha * x[j]
__global__ __launch_bounds__(256) void k_spmm(
    const int* __restrict__ ej, const int* __restrict__ ei,
    const float* __restrict__ ex_buf, const float* __restrict__ denom,
    const float* __restrict__ x, float* __restrict__ out) {
    int wave = (blockIdx.x * blockDim.x + threadIdx.x) >> 6;
    int lane = threadIdx.x & 63;
    if (wave >= E_EDGES) return;
    int j = ej[wave];
    int i = ei[wave];
    float alpha = ex_buf[wave] / (denom[j] + EPS_DEN);
    const float* xr = x + (size_t)j * HDIM;
    float v0 = xr[lane] * alpha;
    float v1 = xr[lane + 64] * alpha;
    float* orow = out + (size_t)i * HDIM;
    atomicAdd(&orow[lane], v0);
    atomicAdd(&orow[lane + 64], v1);
}

// K5: final ReLU over out (vectorized float4, grid-stride)
__global__ __launch_bounds__(256) void k_relu(float4* __restrict__ out, int n4) {
    int idx = blockIdx.x * blockDim.x + threadIdx.x;
    int stride = gridDim.x * blockDim.x;
    for (; idx < n4; idx += stride) {
        float4 v = out[idx];
        v.x = fmaxf(v.x, 0.f);
        v.y = fmaxf(v.y, 0.f);
        v.z = fmaxf(v.z, 0.f);
        v.w = fmaxf(v.w, 0.f);
        out[idx] = v;
    }
}

extern "C" void kernel_launch(void* const* d_in, const int* in_sizes, int n_in,
                              void* d_out, int out_size, void* d_ws, size_t ws_size,
                              hipStream_t stream) {
    const float* x   = (const float*)d_in[0];
    const int*   eidx = (const int*)d_in[1];   // [2, E] int32: row0 = j, row1 = i
    // d_in[2] = line_graph_val (unused by reference)
    const float* w_i = (const float*)d_in[3];
    const float* w_j = (const float*)d_in[4];
    float* out = (float*)d_out;

    const int* ej = eidx;
    const int* ei = eidx + E_EDGES;

    // workspace layout (floats/uints):
    // s_i [0,N)  s_j [N,2N)  segmax [2N,3N)  denom [3N,4N)  e_buf [4N,4N+E)
    float*    s_i    = (float*)d_ws;
    float*    s_j    = s_i + N_NODES;
    unsigned* segmax = (unsigned*)(s_j + N_NODES);
    float*    denom  = (float*)(segmax + N_NODES);
    float*    e_buf  = denom + N_NODES;

    // zero: out accumulator + segmax (0 encodes "most negative") + denom
    hipMemsetAsync(d_out, 0, (size_t)N_NODES * HDIM * sizeof(float), stream);
    hipMemsetAsync(segmax, 0, 2u * N_NODES * sizeof(unsigned), stream);

    // K1: scores — one wave per node
    {
        int waves = N_NODES;
        int blocks = (waves * 64 + 255) / 256;
        k_scores<<<blocks, 256, 0, stream>>>(x, w_i, w_j, s_i, s_j);
    }
    // K2: edge score + segment max
    {
        int blocks = (E_EDGES + 255) / 256;
        k_edge_max<<<blocks, 256, 0, stream>>>(ej, ei, s_i, s_j, e_buf, segmax);
    }
    // K3: exp + segment sum
    {
        int blocks = (E_EDGES + 255) / 256;
        k_edge_exp<<<blocks, 256, 0, stream>>>(ej, e_buf, segmax, denom);
    }
    // K4: SPMM scatter — one wave per edge
    {
        int blocks = (E_EDGES * 64 + 255) / 256;
        k_spmm<<<blocks, 256, 0, stream>>>(ej, ei, e_buf, denom, x, out);
    }
    // K5: ReLU
    {
        int n4 = N_NODES * HDIM / 4;
        int blocks = 2048;
        k_relu<<<blocks, 256, 0, stream>>>((float4*)d_out, n4);
    }
}

// Round 2
// 633.635 us; speedup vs baseline: 1.3242x; 1.3242x over previous
//
#include <hip/hip_runtime.h>
#include <math.h>

#define N_NODES 100000
#define E_EDGES 1600000
#define HDIM 128
#define NEG_SLOPE 0.01f
#define EPS_DEN 1e-16f

// ---- orderable-uint encoding for float atomicMax ----
__device__ __forceinline__ unsigned enc_f32(float f) {
    unsigned u = __float_as_uint(f);
    return (u & 0x80000000u) ? ~u : (u | 0x80000000u);
}
__device__ __forceinline__ float dec_f32(unsigned u) {
    return (u & 0x80000000u) ? __uint_as_float(u & 0x7FFFFFFFu)
                             : __uint_as_float(~u);
}

// K1: per-node scores s_i = x.w_i, s_j = x.w_j  (one wave per node)
__global__ __launch_bounds__(256) void k_scores(
    const float* __restrict__ x, const float* __restrict__ w_i,
    const float* __restrict__ w_j, float* __restrict__ s_i,
    float* __restrict__ s_j) {
    int wave = (blockIdx.x * blockDim.x + threadIdx.x) >> 6;
    int lane = threadIdx.x & 63;
    if (wave >= N_NODES) return;
    const float* row = x + (size_t)wave * HDIM;
    float a0 = row[lane];
    float a1 = row[lane + 64];
    float vi = a0 * w_i[lane] + a1 * w_i[lane + 64];
    float vj = a0 * w_j[lane] + a1 * w_j[lane + 64];
#pragma unroll
    for (int off = 32; off; off >>= 1) {
        vi += __shfl_down(vi, off);
        vj += __shfl_down(vj, off);
    }
    if (lane == 0) {
        s_i[wave] = vi;
        s_j[wave] = vj;
    }
}

// K2: per-edge score e = leaky_relu(s_i[i]+s_j[j]); segmax over j; histogram over i
__global__ __launch_bounds__(256) void k_edge_max(
    const int* __restrict__ ej, const int* __restrict__ ei,
    const float* __restrict__ s_i, const float* __restrict__ s_j,
    float* __restrict__ e_buf, unsigned* __restrict__ segmax,
    int* __restrict__ counts) {
    int t = blockIdx.x * blockDim.x + threadIdx.x;
    if (t >= E_EDGES) return;
    int j = ej[t];
    int i = ei[t];
    float e = s_i[i] + s_j[j];
    e = e > 0.f ? e : NEG_SLOPE * e;
    e_buf[t] = e;
    atomicMax(&segmax[j], enc_f32(e));
    atomicAdd(&counts[i], 1);
}

// K3: ex = exp(e - max[j]); denom[j] += ex   (in place over e_buf)
__global__ __launch_bounds__(256) void k_edge_exp(
    const int* __restrict__ ej, float* __restrict__ e_buf,
    const unsigned* __restrict__ segmax, float* __restrict__ denom) {
    int t = blockIdx.x * blockDim.x + threadIdx.x;
    if (t >= E_EDGES) return;
    int j = ej[t];
    float m = dec_f32(segmax[j]);
    float ex = expf(e_buf[t] - m);
    e_buf[t] = ex;
    atomicAdd(&denom[j], ex);
}

// K4: single-block exclusive scan over counts (in place -> row offsets)
__global__ __launch_bounds__(1024) void k_scan(int* __restrict__ data, int n) {
    __shared__ int sums[1024];
    int t = threadIdx.x;
    int strip = (n + 1023) >> 10;
    int begin = t * strip;
    int end = begin + strip;
    if (end > n) end = n;
    int s = 0;
    for (int k = begin; k < end; ++k) s += data[k];
    sums[t] = s;
    __syncthreads();
    for (int off = 1; off < 1024; off <<= 1) {
        int v = (t >= off) ? sums[t - off] : 0;
        __syncthreads();
        sums[t] += v;
        __syncthreads();
    }
    int pref = (t == 0) ? 0 : sums[t - 1];
    for (int k = begin; k < end; ++k) {
        int v = data[k];
        data[k] = pref;
        pref += v;
    }
}

// K5: scatter edges into CSR (by destination i); alpha finalized here.
// rowoff is mutated: afterwards rowoff[i] == original rowoff[i+1].
__global__ __launch_bounds__(256) void k_scatter(
    const int* __restrict__ ej, const int* __restrict__ ei,
    const float* __restrict__ ex_buf, const float* __restrict__ denom,
    int* __restrict__ rowoff, int* __restrict__ csr_col,
    float* __restrict__ csr_alpha) {
    int t = blockIdx.x * blockDim.x + threadIdx.x;
    if (t >= E_EDGES) return;
    int j = ej[t];
    int i = ei[t];
    float alpha = ex_buf[t] / (denom[j] + EPS_DEN);
    int pos = atomicAdd(&rowoff[i], 1);
    csr_col[pos] = j;
    csr_alpha[pos] = alpha;
}

// K6: gather SPMM + ReLU — one wave per destination node
__global__ __launch_bounds__(256) void k_gather(
    const int* __restrict__ rowoff, const int* __restrict__ csr_col,
    const float* __restrict__ csr_alpha, const float* __restrict__ x,
    float* __restrict__ out) {
    int node = (blockIdx.x * blockDim.x + threadIdx.x) >> 6;
    int lane = threadIdx.x & 63;
    if (node >= N_NODES) return;
    // post-scatter: rowoff[i] = inclusive end; start = rowoff[i-1] (0 for i=0)
    int end = rowoff[node];
    int start = (node == 0) ? 0 : rowoff[node - 1];
    float acc0 = 0.f, acc1 = 0.f;
    for (int base = start; base < end; base += 64) {
        int m = end - base;
        if (m > 64) m = 64;
        int jv = 0;
        float av = 0.f;
        if (lane < m) {
            jv = csr_col[base + lane];
            av = csr_alpha[base + lane];
        }
        for (int e = 0; e < m; ++e) {
            int j = __shfl(jv, e);
            float a = __shfl(av, e);
            const float* xr = x + (size_t)j * HDIM;
            acc0 += a * xr[lane];
            acc1 += a * xr[lane + 64];
        }
    }
    float* orow = out + (size_t)node * HDIM;
    orow[lane]      = fmaxf(acc0, 0.f);
    orow[lane + 64] = fmaxf(acc1, 0.f);
}

extern "C" void kernel_launch(void* const* d_in, const int* in_sizes, int n_in,
                              void* d_out, int out_size, void* d_ws, size_t ws_size,
                              hipStream_t stream) {
    const float* x    = (const float*)d_in[0];
    const int*   eidx = (const int*)d_in[1];   // [2, E] int32: row0 = j, row1 = i
    const float* w_i  = (const float*)d_in[3];
    const float* w_j  = (const float*)d_in[4];
    float* out = (float*)d_out;

    const int* ej = eidx;
    const int* ei = eidx + E_EDGES;

    // workspace layout (4B units):
    // s_i[N] s_j[N] segmax[N] denom[N] rowoff[N] e_buf[E] csr_col[E] csr_alpha[E]
    float*    s_i    = (float*)d_ws;
    float*    s_j    = s_i + N_NODES;
    unsigned* segmax = (unsigned*)(s_j + N_NODES);
    float*    denom  = (float*)(segmax + N_NODES);
    int*      rowoff = (int*)(denom + N_NODES);
    float*    e_buf  = (float*)(rowoff + N_NODES);
    int*      csr_col   = (int*)(e_buf + E_EDGES);
    float*    csr_alpha = (float*)(csr_col + E_EDGES);

    // zero segmax (0 encodes -inf), denom, rowoff (contiguous 3N words)
    hipMemsetAsync(segmax, 0, 3u * N_NODES * sizeof(unsigned), stream);

    // K1: scores — one wave per node
    k_scores<<<(N_NODES * 64 + 255) / 256, 256, 0, stream>>>(x, w_i, w_j, s_i, s_j);
    // K2: edge score + segmax + dest histogram
    k_edge_max<<<(E_EDGES + 255) / 256, 256, 0, stream>>>(ej, ei, s_i, s_j, e_buf,
                                                          segmax, rowoff);
    // K3: exp + denom
    k_edge_exp<<<(E_EDGES + 255) / 256, 256, 0, stream>>>(ej, e_buf, segmax, denom);
    // K4: scan counts -> row offsets
    k_scan<<<1, 1024, 0, stream>>>(rowoff, N_NODES);
    // K5: scatter into CSR with alpha
    k_scatter<<<(E_EDGES + 255) / 256, 256, 0, stream>>>(ej, ei, e_buf, denom,
                                                         rowoff, csr_col, csr_alpha);
    // K6: gather SPMM + ReLU
    k_gather<<<(N_NODES * 64 + 255) / 256, 256, 0, stream>>>(rowoff, csr_col,
                                                             csr_alpha, x, out);
}

// Round 3
// 480.575 us; speedup vs baseline: 1.7459x; 1.3185x over previous
//
#include <hip/hip_runtime.h>
#include <math.h>

#define N_NODES 100000
#define E_EDGES 1600000
#define HDIM 128
#define NEG_SLOPE 0.01f
#define EPS_DEN 1e-16f

#define SCAN_BLOCKS 256
#define SCAN_TPB 256
// per-block chunk and per-thread strip for the hierarchical scan
#define SCAN_CHUNK ((N_NODES + SCAN_BLOCKS - 1) / SCAN_BLOCKS)          // 391
#define SCAN_STRIP ((SCAN_CHUNK + SCAN_TPB - 1) / SCAN_TPB)             // 2

// ---- orderable-uint encoding for float atomicMax ----
__device__ __forceinline__ unsigned enc_f32(float f) {
    unsigned u = __float_as_uint(f);
    return (u & 0x80000000u) ? ~u : (u | 0x80000000u);
}
__device__ __forceinline__ float dec_f32(unsigned u) {
    return (u & 0x80000000u) ? __uint_as_float(u & 0x7FFFFFFFu)
                             : __uint_as_float(~u);
}

// K1: per-node scores s_i = x.w_i, s_j = x.w_j  (one wave per node)
__global__ __launch_bounds__(256) void k_scores(
    const float* __restrict__ x, const float* __restrict__ w_i,
    const float* __restrict__ w_j, float* __restrict__ s_i,
    float* __restrict__ s_j) {
    int wave = (blockIdx.x * blockDim.x + threadIdx.x) >> 6;
    int lane = threadIdx.x & 63;
    if (wave >= N_NODES) return;
    const float* row = x + (size_t)wave * HDIM;
    float a0 = row[lane];
    float a1 = row[lane + 64];
    float vi = a0 * w_i[lane] + a1 * w_i[lane + 64];
    float vj = a0 * w_j[lane] + a1 * w_j[lane + 64];
#pragma unroll
    for (int off = 32; off; off >>= 1) {
        vi += __shfl_down(vi, off);
        vj += __shfl_down(vj, off);
    }
    if (lane == 0) {
        s_i[wave] = vi;
        s_j[wave] = vj;
    }
}

// K2: per-edge score e = leaky_relu(s_i[i]+s_j[j]); segmax over j; histogram over i
__global__ __launch_bounds__(256) void k_edge_max(
    const int* __restrict__ ej, const int* __restrict__ ei,
    const float* __restrict__ s_i, const float* __restrict__ s_j,
    float* __restrict__ e_buf, unsigned* __restrict__ segmax,
    int* __restrict__ counts) {
    int t = blockIdx.x * blockDim.x + threadIdx.x;
    if (t >= E_EDGES) return;
    int j = ej[t];
    int i = ei[t];
    float e = s_i[i] + s_j[j];
    e = e > 0.f ? e : NEG_SLOPE * e;
    e_buf[t] = e;
    atomicMax(&segmax[j], enc_f32(e));
    atomicAdd(&counts[i], 1);
}

// K3: ex = exp(e - max[j]); denom[j] += ex   (in place over e_buf)
__global__ __launch_bounds__(256) void k_edge_exp(
    const int* __restrict__ ej, float* __restrict__ e_buf,
    const unsigned* __restrict__ segmax, float* __restrict__ denom) {
    int t = blockIdx.x * blockDim.x + threadIdx.x;
    if (t >= E_EDGES) return;
    int j = ej[t];
    float m = dec_f32(segmax[j]);
    float ex = expf(e_buf[t] - m);
    e_buf[t] = ex;
    atomicAdd(&denom[j], ex);
}

// ---- hierarchical exclusive scan over counts (3 phases) ----
// Phase A: per-block chunk sums
__global__ __launch_bounds__(SCAN_TPB) void k_scanA(
    const int* __restrict__ data, int n, int* __restrict__ blocksum) {
    __shared__ int red[SCAN_TPB];
    int b = blockIdx.x, t = threadIdx.x;
    int begin = b * SCAN_CHUNK + t * SCAN_STRIP;
    int end = begin + SCAN_STRIP;
    int lim = (b + 1) * SCAN_CHUNK;
    if (lim > n) lim = n;
    if (end > lim) end = lim;
    int s = 0;
    for (int k = begin; k < end; ++k) s += data[k];
    red[t] = s;
    __syncthreads();
    for (int off = SCAN_TPB / 2; off; off >>= 1) {
        if (t < off) red[t] += red[t + off];
        __syncthreads();
    }
    if (t == 0) blocksum[b] = red[0];
}

// Phase B: single block exclusive-scans the block sums (in place)
__global__ __launch_bounds__(SCAN_BLOCKS) void k_scanB(int* __restrict__ blocksum) {
    __shared__ int s[SCAN_BLOCKS];
    int t = threadIdx.x;
    s[t] = blocksum[t];
    __syncthreads();
    for (int off = 1; off < SCAN_BLOCKS; off <<= 1) {
        int v = (t >= off) ? s[t - off] : 0;
        __syncthreads();
        s[t] += v;
        __syncthreads();
    }
    blocksum[t] = (t == 0) ? 0 : s[t - 1];   // exclusive
}

// Phase C: local exclusive scan + block prefix, write back in place
__global__ __launch_bounds__(SCAN_TPB) void k_scanC(
    int* __restrict__ data, int n, const int* __restrict__ blocksum) {
    __shared__ int s[SCAN_TPB];
    int b = blockIdx.x, t = threadIdx.x;
    int begin = b * SCAN_CHUNK + t * SCAN_STRIP;
    int end = begin + SCAN_STRIP;
    int lim = (b + 1) * SCAN_CHUNK;
    if (lim > n) lim = n;
    if (end > lim) end = lim;
    int v0 = 0, v1 = 0;            // SCAN_STRIP == 2
    if (begin < lim)      v0 = data[begin];
    if (begin + 1 < lim)  v1 = data[begin + 1];
    s[t] = v0 + v1;
    __syncthreads();
    for (int off = 1; off < SCAN_TPB; off <<= 1) {
        int v = (t >= off) ? s[t - off] : 0;
        __syncthreads();
        s[t] += v;
        __syncthreads();
    }
    int pref = blocksum[b] + ((t == 0) ? 0 : s[t - 1]);
    if (begin < lim)     data[begin] = pref;
    if (begin + 1 < lim) data[begin + 1] = pref + v0;
}

// K5: scatter edges into CSR (by destination i); alpha finalized here.
// rowoff is mutated: afterwards rowoff[i] == original rowoff[i+1].
__global__ __launch_bounds__(256) void k_scatter(
    const int* __restrict__ ej, const int* __restrict__ ei,
    const float* __restrict__ ex_buf, const float* __restrict__ denom,
    int* __restrict__ rowoff, int* __restrict__ csr_col,
    float* __restrict__ csr_alpha) {
    int t = blockIdx.x * blockDim.x + threadIdx.x;
    if (t >= E_EDGES) return;
    int j = ej[t];
    int i = ei[t];
    float alpha = ex_buf[t] / (denom[j] + EPS_DEN);
    int pos = atomicAdd(&rowoff[i], 1);
    csr_col[pos] = j;
    csr_alpha[pos] = alpha;
}

// K6: gather SPMM + ReLU — one wave per destination node
__global__ __launch_bounds__(256) void k_gather(
    const int* __restrict__ rowoff, const int* __restrict__ csr_col,
    const float* __restrict__ csr_alpha, const float* __restrict__ x,
    float* __restrict__ out) {
    int node = (blockIdx.x * blockDim.x + threadIdx.x) >> 6;
    int lane = threadIdx.x & 63;
    if (node >= N_NODES) return;
    // post-scatter: rowoff[i] = inclusive end; start = rowoff[i-1] (0 for i=0)
    int end = rowoff[node];
    int start = (node == 0) ? 0 : rowoff[node - 1];
    float acc0 = 0.f, acc1 = 0.f;
    for (int base = start; base < end; base += 64) {
        int m = end - base;
        if (m > 64) m = 64;
        int jv = 0;
        float av = 0.f;
        if (lane < m) {
            jv = csr_col[base + lane];
            av = csr_alpha[base + lane];
        }
        for (int e = 0; e < m; ++e) {
            int j = __shfl(jv, e);
            float a = __shfl(av, e);
            const float* xr = x + (size_t)j * HDIM;
            acc0 += a * xr[lane];
            acc1 += a * xr[lane + 64];
        }
    }
    float* orow = out + (size_t)node * HDIM;
    orow[lane]      = fmaxf(acc0, 0.f);
    orow[lane + 64] = fmaxf(acc1, 0.f);
}

extern "C" void kernel_launch(void* const* d_in, const int* in_sizes, int n_in,
                              void* d_out, int out_size, void* d_ws, size_t ws_size,
                              hipStream_t stream) {
    const float* x    = (const float*)d_in[0];
    const int*   eidx = (const int*)d_in[1];   // [2, E] int32: row0 = j, row1 = i
    const float* w_i  = (const float*)d_in[3];
    const float* w_j  = (const float*)d_in[4];
    float* out = (float*)d_out;

    const int* ej = eidx;
    const int* ei = eidx + E_EDGES;

    // workspace layout (4B units):
    // s_i[N] s_j[N] segmax[N] denom[N] rowoff[N] blocksum[SCAN_BLOCKS]
    // e_buf[E] csr_col[E] csr_alpha[E]
    float*    s_i    = (float*)d_ws;
    float*    s_j    = s_i + N_NODES;
    unsigned* segmax = (unsigned*)(s_j + N_NODES);
    float*    denom  = (float*)(segmax + N_NODES);
    int*      rowoff = (int*)(denom + N_NODES);
    int*      blocksum = (int*)(rowoff + N_NODES);
    float*    e_buf  = (float*)(blocksum + SCAN_BLOCKS);
    int*      csr_col   = (int*)(e_buf + E_EDGES);
    float*    csr_alpha = (float*)(csr_col + E_EDGES);

    // zero segmax (0 encodes -inf), denom, rowoff (contiguous 3N words)
    hipMemsetAsync(segmax, 0, 3u * N_NODES * sizeof(unsigned), stream);

    // K1: scores — one wave per node
    k_scores<<<(N_NODES * 64 + 255) / 256, 256, 0, stream>>>(x, w_i, w_j, s_i, s_j);
    // K2: edge score + segmax + dest histogram
    k_edge_max<<<(E_EDGES + 255) / 256, 256, 0, stream>>>(ej, ei, s_i, s_j, e_buf,
                                                          segmax, rowoff);
    // K3: exp + denom
    k_edge_exp<<<(E_EDGES + 255) / 256, 256, 0, stream>>>(ej, e_buf, segmax, denom);
    // K4: hierarchical scan counts -> exclusive row offsets
    k_scanA<<<SCAN_BLOCKS, SCAN_TPB, 0, stream>>>(rowoff, N_NODES, blocksum);
    k_scanB<<<1, SCAN_BLOCKS, 0, stream>>>(blocksum);
    k_scanC<<<SCAN_BLOCKS, SCAN_TPB, 0, stream>>>(rowoff, N_NODES, blocksum);
    // K5: scatter into CSR with alpha
    k_scatter<<<(E_EDGES + 255) / 256, 256, 0, stream>>>(ej, ei, e_buf, denom,
                                                         rowoff, csr_col, csr_alpha);
    // K6: gather SPMM + ReLU
    k_gather<<<(N_NODES * 64 + 255) / 256, 256, 0, stream>>>(rowoff, csr_col,
                                                             csr_alpha, x, out);
}

// Round 4
// 308.550 us; speedup vs baseline: 2.7194x; 1.5575x over previous
//
#include <hip/hip_runtime.h>
#include <math.h>

#define N_NODES 100000
#define E_EDGES 1600000
#define HDIM 128
#define NEG_SLOPE 0.01f
#define EPS_DEN 1e-16f
#define ROW_CAP 64

#define SCAN_BLOCKS 256
#define SCAN_TPB 256
#define SCAN_CHUNK ((N_NODES + SCAN_BLOCKS - 1) / SCAN_BLOCKS)   // 391
#define SCAN_STRIP ((SCAN_CHUNK + SCAN_TPB - 1) / SCAN_TPB)      // 2

__device__ __forceinline__ float lrelu(float e) {
    return e > 0.f ? e : NEG_SLOPE * e;
}

// K1: per-node scores s_i = x.w_i, s_j = x.w_j  (one wave per node, float2 loads)
__global__ __launch_bounds__(256) void k_scores(
    const float* __restrict__ x, const float* __restrict__ w_i,
    const float* __restrict__ w_j, float* __restrict__ s_i,
    float* __restrict__ s_j) {
    int wave = (blockIdx.x * blockDim.x + threadIdx.x) >> 6;
    int lane = threadIdx.x & 63;
    if (wave >= N_NODES) return;
    const float2* row = (const float2*)(x + (size_t)wave * HDIM);
    float2 v  = row[lane];
    float2 wi = ((const float2*)w_i)[lane];
    float2 wj = ((const float2*)w_j)[lane];
    float vi = v.x * wi.x + v.y * wi.y;
    float vj = v.x * wj.x + v.y * wj.y;
#pragma unroll
    for (int off = 32; off; off >>= 1) {
        vi += __shfl_down(vi, off);
        vj += __shfl_down(vj, off);
    }
    if (lane == 0) {
        s_i[wave] = vi;
        s_j[wave] = vj;
    }
}

// K2: denom[j] += exp(lrelu(s_i[i]+s_j[j])); optional dest histogram
template <bool COUNT>
__global__ __launch_bounds__(256) void k_denom(
    const int* __restrict__ ej, const int* __restrict__ ei,
    const float* __restrict__ s_i, const float* __restrict__ s_j,
    float* __restrict__ denom, int* __restrict__ counts) {
    int t = blockIdx.x * blockDim.x + threadIdx.x;
    if (t >= E_EDGES) return;
    int j = ej[t];
    int i = ei[t];
    float ex = expf(lrelu(s_i[i] + s_j[j]));
    atomicAdd(&denom[j], ex);
    if (COUNT) atomicAdd(&counts[i], 1);
}

// ---- hierarchical scan (dense fallback path only) ----
__global__ __launch_bounds__(SCAN_TPB) void k_scanA(
    const int* __restrict__ data, int n, int* __restrict__ blocksum) {
    __shared__ int red[SCAN_TPB];
    int b = blockIdx.x, t = threadIdx.x;
    int begin = b * SCAN_CHUNK + t * SCAN_STRIP;
    int lim = (b + 1) * SCAN_CHUNK;
    if (lim > n) lim = n;
    int end = begin + SCAN_STRIP;
    if (end > lim) end = lim;
    int s = 0;
    for (int k = begin; k < end; ++k) s += data[k];
    red[t] = s;
    __syncthreads();
    for (int off = SCAN_TPB / 2; off; off >>= 1) {
        if (t < off) red[t] += red[t + off];
        __syncthreads();
    }
    if (t == 0) blocksum[b] = red[0];
}

__global__ __launch_bounds__(SCAN_BLOCKS) void k_scanB(int* __restrict__ blocksum) {
    __shared__ int s[SCAN_BLOCKS];
    int t = threadIdx.x;
    s[t] = blocksum[t];
    __syncthreads();
    for (int off = 1; off < SCAN_BLOCKS; off <<= 1) {
        int v = (t >= off) ? s[t - off] : 0;
        __syncthreads();
        s[t] += v;
        __syncthreads();
    }
    blocksum[t] = (t == 0) ? 0 : s[t - 1];
}

__global__ __launch_bounds__(SCAN_TPB) void k_scanC(
    int* __restrict__ data, int n, const int* __restrict__ blocksum) {
    __shared__ int s[SCAN_TPB];
    int b = blockIdx.x, t = threadIdx.x;
    int begin = b * SCAN_CHUNK + t * SCAN_STRIP;
    int lim = (b + 1) * SCAN_CHUNK;
    if (lim > n) lim = n;
    int v0 = 0, v1 = 0;            // SCAN_STRIP == 2
    if (begin < lim)      v0 = data[begin];
    if (begin + 1 < lim)  v1 = data[begin + 1];
    s[t] = v0 + v1;
    __syncthreads();
    for (int off = 1; off < SCAN_TPB; off <<= 1) {
        int v = (t >= off) ? s[t - off] : 0;
        __syncthreads();
        s[t] += v;
        __syncthreads();
    }
    int pref = blocksum[b] + ((t == 0) ? 0 : s[t - 1]);
    if (begin < lim)     data[begin] = pref;
    if (begin + 1 < lim) data[begin + 1] = pref + v0;
}

// K3a (padded): scatter edge into fixed-cap row; cursor doubles as row length
__global__ __launch_bounds__(256) void k_scatter_pad(
    const int* __restrict__ ej, const int* __restrict__ ei,
    const float* __restrict__ s_i, const float* __restrict__ s_j,
    const float* __restrict__ denom, int* __restrict__ cursor,
    int2* __restrict__ csr) {
    int t = blockIdx.x * blockDim.x + threadIdx.x;
    if (t >= E_EDGES) return;
    int j = ej[t];
    int i = ei[t];
    int slot = atomicAdd(&cursor[i], 1);
    if (slot < ROW_CAP) {
        float ex = expf(lrelu(s_i[i] + s_j[j]));
        float alpha = ex / (denom[j] + EPS_DEN);
        int2 v;
        v.x = j;
        v.y = __float_as_int(alpha);
        csr[(size_t)i * ROW_CAP + slot] = v;
    }
}

// K3b (dense): scatter into scan-derived CSR; rowoff[i] becomes inclusive end
__global__ __launch_bounds__(256) void k_scatter_dense(
    const int* __restrict__ ej, const int* __restrict__ ei,
    const float* __restrict__ s_i, const float* __restrict__ s_j,
    const float* __restrict__ denom, int* __restrict__ rowoff,
    int2* __restrict__ csr) {
    int t = blockIdx.x * blockDim.x + threadIdx.x;
    if (t >= E_EDGES) return;
    int j = ej[t];
    int i = ei[t];
    float ex = expf(lrelu(s_i[i] + s_j[j]));
    float alpha = ex / (denom[j] + EPS_DEN);
    int pos = atomicAdd(&rowoff[i], 1);
    int2 v;
    v.x = j;
    v.y = __float_as_int(alpha);
    csr[pos] = v;
}

// K4: gather SPMM + ReLU — one wave per destination node (float2 x-row loads)
template <bool PAD>
__global__ __launch_bounds__(256) void k_gather(
    const int* __restrict__ meta, const int2* __restrict__ csr,
    const float* __restrict__ x, float* __restrict__ out) {
    int node = (blockIdx.x * blockDim.x + threadIdx.x) >> 6;
    int lane = threadIdx.x & 63;
    if (node >= N_NODES) return;
    int start, len;
    if (PAD) {
        start = node * ROW_CAP;
        len = meta[node];
        if (len > ROW_CAP) len = ROW_CAP;
    } else {
        int end = meta[node];
        start = (node == 0) ? 0 : meta[node - 1];
        len = end - start;
    }
    float acc0 = 0.f, acc1 = 0.f;
    for (int base = start; len > 0; base += 64, len -= 64) {
        int m = len > 64 ? 64 : len;
        int jv = 0, av = 0;
        if (lane < m) {
            int2 v = csr[base + lane];
            jv = v.x;
            av = v.y;
        }
        for (int e = 0; e < m; ++e) {
            int j = __shfl(jv, e);
            float a = __int_as_float(__shfl(av, e));
            const float2* xr = (const float2*)(x + (size_t)j * HDIM);
            float2 v = xr[lane];
            acc0 += a * v.x;
            acc1 += a * v.y;
        }
    }
    float2* orow = (float2*)(out + (size_t)node * HDIM);
    float2 o;
    o.x = fmaxf(acc0, 0.f);
    o.y = fmaxf(acc1, 0.f);
    orow[lane] = o;
}

extern "C" void kernel_launch(void* const* d_in, const int* in_sizes, int n_in,
                              void* d_out, int out_size, void* d_ws, size_t ws_size,
                              hipStream_t stream) {
    const float* x    = (const float*)d_in[0];
    const int*   eidx = (const int*)d_in[1];   // [2, E] int32: row0 = j, row1 = i
    const float* w_i  = (const float*)d_in[3];
    const float* w_j  = (const float*)d_in[4];
    float* out = (float*)d_out;

    const int* ej = eidx;
    const int* ei = eidx + E_EDGES;

    // common prefix: s_i[N] s_j[N] denom[N] cursor/rowoff[N]
    float* s_i    = (float*)d_ws;
    float* s_j    = s_i + N_NODES;
    float* denom  = s_j + N_NODES;
    int*   cursor = (int*)(denom + N_NODES);   // counts/rowoff in dense path

    size_t pfx_bytes = (size_t)4 * N_NODES * sizeof(int);            // 1.6 MB
    size_t need_pad  = pfx_bytes + (size_t)N_NODES * ROW_CAP * sizeof(int2); // ~52.8 MB
    bool use_pad = (ws_size >= need_pad);

    const int EB = (E_EDGES + 255) / 256;
    const int NB = (N_NODES * 64 + 255) / 256;

    if (use_pad) {
        int2* csr = (int2*)((char*)d_ws + pfx_bytes);
        // zero denom + cursor (contiguous 2N words)
        hipMemsetAsync(denom, 0, 2u * N_NODES * sizeof(int), stream);
        k_scores<<<NB, 256, 0, stream>>>(x, w_i, w_j, s_i, s_j);
        k_denom<false><<<EB, 256, 0, stream>>>(ej, ei, s_i, s_j, denom, nullptr);
        k_scatter_pad<<<EB, 256, 0, stream>>>(ej, ei, s_i, s_j, denom, cursor, csr);
        k_gather<true><<<NB, 256, 0, stream>>>(cursor, csr, x, out);
    } else {
        int* blocksum = cursor + N_NODES;
        // csr starts after blocksum, 8B aligned: (4N+256)*4 bytes offset
        int2* csr = (int2*)((char*)d_ws + pfx_bytes + SCAN_BLOCKS * sizeof(int) +
                            N_NODES * 0);  // blocksum then csr
        csr = (int2*)((char*)(blocksum + SCAN_BLOCKS));
        hipMemsetAsync(denom, 0, 2u * N_NODES * sizeof(int), stream);
        k_scores<<<NB, 256, 0, stream>>>(x, w_i, w_j, s_i, s_j);
        k_denom<true><<<EB, 256, 0, stream>>>(ej, ei, s_i, s_j, denom, cursor);
        k_scanA<<<SCAN_BLOCKS, SCAN_TPB, 0, stream>>>(cursor, N_NODES, blocksum);
        k_scanB<<<1, SCAN_BLOCKS, 0, stream>>>(blocksum);
        k_scanC<<<SCAN_BLOCKS, SCAN_TPB, 0, stream>>>(cursor, N_NODES, blocksum);
        k_scatter_dense<<<EB, 256, 0, stream>>>(ej, ei, s_i, s_j, denom, cursor, csr);
        k_gather<false><<<NB, 256, 0, stream>>>(cursor, csr, x, out);
    }
}